// Round 23
// baseline (147.725 us; speedup 1.0000x reference)
//
#include <hip/hip_runtime.h>

// LinearAutoDecoder R23: R20 + interleaved stage-issue (demand smoothing).
// R20 (146.5us, reproduced 147.1) issues all 5 slab-t+1 loads as one burst,
// then is silent through MFMA + barrier; 3 phase-locking blocks/CU leave HBM
// ~70% busy despite 1.4x oversubscription. This spreads the 5 issues across
// the 10-step MFMA kk-loop (one every 2 steps): continuous per-block HBM
// demand, no sched_barrier pins, all other code identical to R20.

constexpr int POS = 63, LAT = 256, DIM = 319, NCH = 192;
constexpr int ROWS = 16;                     // rows per tile
constexpr int PW_DW = NCH * 160;             // 30720 dwords (320 bf16/ch)
constexpr size_t PW_BYTES = (size_t)PW_DW * 4;
constexpr int TILE_DW = ROWS * DIM;          // 5104 dwords
constexpr int TILE_F4 = TILE_DW / 4;         // 1276 float4 per slab
constexpr int GRID = 768;                    // 3 blocks/CU, all resident

typedef __attribute__((ext_vector_type(8))) short short8;
typedef __attribute__((ext_vector_type(4))) float f32x4;

__device__ __forceinline__ unsigned f2bf(float f) {
    unsigned u = __float_as_uint(f);
    return (u + 0x7fffu + ((u >> 16) & 1u)) >> 16;
}

// pw[ch*160 + d] = bf16(w[ch][2d]) | bf16(w[ch][2d+1])<<16 ; k=319 -> 0
__global__ __launch_bounds__(256) void pack_weights(
    const float* __restrict__ Wp, const float* __restrict__ Wf,
    unsigned* __restrict__ pw)
{
    const int idx = blockIdx.x * 256 + threadIdx.x;
    if (idx >= PW_DW) return;
    const int ch = idx / 160, d = idx - ch * 160;
    auto wat = [&](int k) -> float {
        if (k < POS) return Wp[ch * POS + k];
        if (k < DIM) return Wf[ch * LAT + (k - POS)];
        return 0.f;
    };
    pw[idx] = f2bf(wat(2 * d)) | (f2bf(wat(2 * d + 1)) << 16);
}

__global__ __launch_bounds__(256, 3) void lad_mfma5(
    const float4* __restrict__ X4, const int* __restrict__ cid,
    const unsigned* __restrict__ pw, float* __restrict__ out,
    int ntiles, int tpb)
{
    __shared__ float xb[2][TILE_DW];   // 40,832 B -> 3 blocks/CU

    const int thr = threadIdx.x;
    const int l   = thr & 63;
    const int wid = thr >> 6;
    const int n0  = wid * 48;          // wave's channel base
    const int cl  = l & 15;            // row(A) / col(B,C)
    const int q   = l >> 4;            // k-quad

    // B fragments: 48 channels x K=320 in VGPRs.
    short8 Bf[3][10];
#pragma unroll
    for (int nt = 0; nt < 3; ++nt)
#pragma unroll
        for (int kk = 0; kk < 10; ++kk)
            Bf[nt][kk] = *reinterpret_cast<const short8*>(
                pw + (size_t)(n0 + nt * 16 + cl) * 160 + kk * 16 + q * 4);

    const int t0 = blockIdx.x * tpb;
    const int tend = min(t0 + tpb, ntiles);
    if (t0 >= tend) return;

    // Burst stage (prologue only).
    {
        const float4* src = X4 + (size_t)t0 * TILE_F4;
#pragma unroll
        for (int j = 0; j < 5; ++j) {
            const int slot = j * 256 + thr;
            if (slot < TILE_F4)
                __builtin_amdgcn_global_load_lds(
                    (const __attribute__((address_space(1))) unsigned int*)(src + slot),
                    (__attribute__((address_space(3))) unsigned int*)&xb[0][slot * 4],
                    16, 0, 0);
        }
    }
    __syncthreads();                   // prologue drain

    int p = 0;
    for (int t = t0; t < tend; ++t) {
        const bool has_next = (t + 1 < tend);
        const float4* srcn = X4 + (size_t)(has_next ? t + 1 : t) * TILE_F4;
        float* dstn = xb[p ^ 1];

        // cid for this lane's 4 output rows (L1-hot, overlaps MFMA).
        int c3v[4];
#pragma unroll
        for (int j = 0; j < 4; ++j)
            c3v[j] = 3 * cid[(size_t)t * ROWS + q * 4 + j];

        f32x4 acc[3];
#pragma unroll
        for (int nt = 0; nt < 3; ++nt)
            acc[nt] = (f32x4)0.0f;

        // MFMA over K=320 with stage-issue interleaved: one slab-t+1 load
        // every 2 k-steps -> continuous HBM demand instead of a burst.
#pragma unroll
        for (int kk = 0; kk < 10; ++kk) {
            if ((kk & 1) == 0) {
                const int j = kk >> 1;
                const int slot = j * 256 + thr;
                if (has_next && slot < TILE_F4)
                    __builtin_amdgcn_global_load_lds(
                        (const __attribute__((address_space(1))) unsigned int*)(srcn + slot),
                        (__attribute__((address_space(3))) unsigned int*)&dstn[slot * 4],
                        16, 0, 0);
            }
            const float* fp = &xb[p][cl * DIM + kk * 32 + q * 8];
            union { unsigned u[4]; short8 s; } cv;
#pragma unroll
            for (int h = 0; h < 4; ++h) {
                asm("v_cvt_pk_bf16_f32 %0, %1, %2"
                    : "=v"(cv.u[h]) : "v"(fp[2 * h]), "v"(fp[2 * h + 1]));
            }
#pragma unroll
            for (int nt = 0; nt < 3; ++nt)
                acc[nt] = __builtin_amdgcn_mfma_f32_16x16x32_bf16(
                    cv.s, Bf[nt][kk], acc[nt], 0, 0, 0);
        }

        // Sparse direct output (C layout: col=lane&15, row=(lane>>4)*4+j).
#pragma unroll
        for (int j = 0; j < 4; ++j) {
            const int grow = t * ROWS + q * 4 + j;
            const int c3 = c3v[j];
#pragma unroll
            for (int nt = 0; nt < 3; ++nt) {
                const int col = n0 + nt * 16 + cl;
                const unsigned d = (unsigned)(col - c3);
                if (d < 3u)
                    out[(size_t)grow * 3 + d] = acc[nt][j];
            }
        }

        __syncthreads();   // drains slab(t+1) + stores; buffers swap safely
        p ^= 1;
    }
}

// ---------- fallback (R2-style, fp32 weights, no workspace) ----------
template <int CTRL>
__device__ __forceinline__ float dpp_add_step(float x) {
    int s = __builtin_amdgcn_update_dpp(0, __float_as_int(x), CTRL,
                                        0xF, 0xF, true);
    return x + __int_as_float(s);
}
__device__ __forceinline__ float wave_reduce_sum(float x) {
    x = dpp_add_step<0x111>(x);
    x = dpp_add_step<0x112>(x);
    x = dpp_add_step<0x114>(x);
    x = dpp_add_step<0x118>(x);
    x = dpp_add_step<0x142>(x);
    x = dpp_add_step<0x143>(x);
    return x;   // lane 63
}

__global__ __launch_bounds__(256) void lad_fallback(
    const float* __restrict__ X, const int* __restrict__ cid,
    const float* __restrict__ Wp, const float* __restrict__ Wf,
    float* __restrict__ out, int n)
{
    const int lane = threadIdx.x & 63;
    const int wave = (int)((blockIdx.x * blockDim.x + threadIdx.x) >> 6);
    if (wave >= n) return;
    const size_t row = (size_t)wave;
    const float* xrow = X + row * (size_t)DIM;
    const float* xf   = xrow + POS;
    const int c3 = cid[row] * 3;
    const float* wp0 = Wp + (size_t)c3 * POS;
    const float* wf0 = Wf + (size_t)c3 * LAT;
    float a0 = 0.f, a1 = 0.f, a2 = 0.f;
#pragma unroll
    for (int i = 0; i < 4; ++i) {
        const int k = lane + 64 * i;
        const float x = xf[k];
        a0 = fmaf(x, wf0[k], a0);
        a1 = fmaf(x, wf0[k + LAT], a1);
        a2 = fmaf(x, wf0[k + 2 * LAT], a2);
    }
    if (lane < POS) {
        const float x = xrow[lane];
        a0 = fmaf(x, wp0[lane], a0);
        a1 = fmaf(x, wp0[lane + POS], a1);
        a2 = fmaf(x, wp0[lane + 2 * POS], a2);
    }
    a0 = wave_reduce_sum(a0);
    a1 = wave_reduce_sum(a1);
    a2 = wave_reduce_sum(a2);
    if (lane == 63) {
        float* o = out + row * 3;
        o[0] = a0; o[1] = a1; o[2] = a2;
    }
}

extern "C" void kernel_launch(void* const* d_in, const int* in_sizes, int n_in,
                              void* d_out, int out_size, void* d_ws, size_t ws_size,
                              hipStream_t stream) {
    const float* X   = (const float*)d_in[0];
    const int*   cid = (const int*)d_in[1];
    const float* Wp  = (const float*)d_in[2];
    const float* Wf  = (const float*)d_in[3];
    float* out = (float*)d_out;
    const int n = in_sizes[1];

    if (ws_size >= PW_BYTES && n > 0 && (n % ROWS) == 0) {
        unsigned* pw = (unsigned*)d_ws;
        pack_weights<<<(PW_DW + 255) / 256, 256, 0, stream>>>(Wp, Wf, pw);
        const int ntiles = n / ROWS;                       // 32768
        const int tpb = (ntiles + GRID - 1) / GRID;        // 43
        lad_mfma5<<<GRID, 256, 0, stream>>>((const float4*)X, cid, pw, out,
                                            ntiles, tpb);
    } else {
        const int blocks = (n + 3) / 4;
        lad_fallback<<<blocks, 256, 0, stream>>>(X, cid, Wp, Wf, out, n);
    }
}